// Round 4
// baseline (1992.463 us; speedup 1.0000x reference)
//
#include <hip/hip_runtime.h>

#define N_NODES 500000
#define N_EDGES 16000000
#define NB 1954          // ceil(N_NODES/256)
#define NPB_LOG 9
#define NPB 512          // nodes per bucket
#define NBUCK 977        // ceil(N_NODES/NPB)
#define NBUCK_PAD 1024
#define CH 32768         // edges per bucket_scatter block
#define NSB 489          // ceil(N_EDGES/CH)
#define DBINS 256        // degree bins (clamped)
#define DNPB 1024        // nodes per degree-sort block
#define NDB 489          // ceil(N_NODES/DNPB)

// ============================================================================
// Two-level counting sort (LDS atomics) -> CSR (off, S)
// ============================================================================

__global__ void bucket_hist(const int* __restrict__ dst, int* __restrict__ ghist) {
    __shared__ int lhist[NBUCK_PAD];
    for (int t = threadIdx.x; t < NBUCK_PAD; t += 256) lhist[t] = 0;
    __syncthreads();
    int stride = gridDim.x * 256;
    for (int i = blockIdx.x * 256 + threadIdx.x; i < N_EDGES; i += stride) {
        atomicAdd(&lhist[dst[i] >> NPB_LOG], 1);
    }
    __syncthreads();
    for (int t = threadIdx.x; t < NBUCK_PAD; t += 256) {
        int c = lhist[t];
        if (c) atomicAdd(&ghist[t], c);
    }
}

__global__ void bucket_scan(int* __restrict__ gcur, int* __restrict__ bbase) {
    __shared__ int s[256];
    int t = threadIdx.x;
    int v[4], sum = 0, loc[4];
#pragma unroll
    for (int j = 0; j < 4; ++j) {
        v[j] = gcur[t * 4 + j];
        loc[j] = sum;
        sum += v[j];
    }
    s[t] = sum;
    __syncthreads();
    for (int o = 1; o < 256; o <<= 1) {
        int x = (t >= o) ? s[t - o] : 0;
        __syncthreads();
        s[t] += x;
        __syncthreads();
    }
    int excl = s[t] - sum;
#pragma unroll
    for (int j = 0; j < 4; ++j) {
        int e = excl + loc[j];
        bbase[t * 4 + j] = e;
        gcur[t * 4 + j] = e;
    }
    if (t == 255) bbase[NBUCK_PAD] = s[255];
}

__global__ void bucket_scatter(const int* __restrict__ src, const int* __restrict__ dst,
                               int* __restrict__ gcur, int* __restrict__ P) {
    __shared__ int lhist[NBUCK_PAD];
    __shared__ int lcur[NBUCK_PAD];
    for (int t = threadIdx.x; t < NBUCK_PAD; t += 256) lhist[t] = 0;
    __syncthreads();
    int e0 = blockIdx.x * CH;
    int e1 = min(e0 + CH, N_EDGES);
    for (int i = e0 + threadIdx.x; i < e1; i += 256) {
        atomicAdd(&lhist[dst[i] >> NPB_LOG], 1);
    }
    __syncthreads();
    for (int t = threadIdx.x; t < NBUCK_PAD; t += 256) {
        int c = lhist[t];
        lcur[t] = c ? atomicAdd(&gcur[t], c) : 0;
    }
    __syncthreads();
    for (int i = e0 + threadIdx.x; i < e1; i += 256) {
        int d = dst[i];
        int s = src[i];
        int b = d >> NPB_LOG;
        int pos = atomicAdd(&lcur[b], 1);
        P[pos] = ((d & (NPB - 1)) << 19) | s;
    }
}

__global__ void fine_sort(const int* __restrict__ P, const int* __restrict__ bbase,
                          int* __restrict__ off, int* __restrict__ S) {
    __shared__ int lhist[NPB];
    __shared__ int lexcl[NPB];
    __shared__ int sscan[256];
    int t = threadIdx.x;
    int b = blockIdx.x;
    int bb = bbase[b];
    int be = bbase[b + 1];
    int node0 = b << NPB_LOG;

    lhist[t] = 0;
    lhist[t + 256] = 0;
    __syncthreads();
    for (int j = bb + t; j < be; j += 256) {
        atomicAdd(&lhist[P[j] >> 19], 1);
    }
    __syncthreads();

    int a0 = lhist[2 * t], a1 = lhist[2 * t + 1];
    int ps = a0 + a1;
    sscan[t] = ps;
    __syncthreads();
    for (int o = 1; o < 256; o <<= 1) {
        int x = (t >= o) ? sscan[t - o] : 0;
        __syncthreads();
        sscan[t] += x;
        __syncthreads();
    }
    int pe = sscan[t] - ps;
    lexcl[2 * t] = pe;
    lexcl[2 * t + 1] = pe + a0;
    __syncthreads();

#pragma unroll
    for (int j = 0; j < 2; ++j) {
        int idx = t + j * 256;
        int ng = node0 + idx;
        if (ng < N_NODES) off[ng] = bb + lexcl[idx];
        lhist[idx] = lexcl[idx];
    }
    if (b == NBUCK - 1 && t == 0) off[N_NODES] = N_EDGES;
    __syncthreads();

    for (int j = bb + t; j < be; j += 256) {
        int p = P[j];
        int n = p >> 19;
        int s = p & 0x7FFFF;
        int pos = atomicAdd(&lhist[n], 1);
        S[bb + pos] = s;
    }
}

// ============================================================================
// Degree-sorted node permutation (LPT: heaviest degree first)
// ============================================================================

__device__ __forceinline__ int deg_bin(int d) {
    // descending: heavy degrees -> low bins -> processed first
    return (DBINS - 1) - min(d, DBINS - 1);
}

__global__ void deg_hist(const int* __restrict__ off, int* __restrict__ dcur) {
    __shared__ int lh[DBINS];
    int t = threadIdx.x;
    lh[t] = 0;
    __syncthreads();
    int n0 = blockIdx.x * DNPB;
    int n1 = min(n0 + DNPB, N_NODES);
    for (int i = n0 + t; i < n1; i += 256) {
        atomicAdd(&lh[deg_bin(off[i + 1] - off[i])], 1);
    }
    __syncthreads();
    int c = lh[t];
    if (c) atomicAdd(&dcur[t], c);
}

__global__ void deg_scan(int* __restrict__ dcur) {
    __shared__ int s[256];
    int t = threadIdx.x;
    int v = dcur[t];
    s[t] = v;
    __syncthreads();
    for (int o = 1; o < 256; o <<= 1) {
        int x = (t >= o) ? s[t - o] : 0;
        __syncthreads();
        s[t] += x;
        __syncthreads();
    }
    dcur[t] = s[t] - v;  // exclusive base, reused as global cursor
}

__global__ void deg_scatter(const int* __restrict__ off, int* __restrict__ dcur,
                            int* __restrict__ perm) {
    __shared__ int lh[DBINS];
    __shared__ int lbase[DBINS];
    int t = threadIdx.x;
    lh[t] = 0;
    __syncthreads();
    int n0 = blockIdx.x * DNPB;
    int n1 = min(n0 + DNPB, N_NODES);
    for (int i = n0 + t; i < n1; i += 256) {
        atomicAdd(&lh[deg_bin(off[i + 1] - off[i])], 1);
    }
    __syncthreads();
    int c = lh[t];
    lbase[t] = c ? atomicAdd(&dcur[t], c) : 0;
    lh[t] = 0;  // reuse as local cursor
    __syncthreads();
    for (int i = n0 + t; i < n1; i += 256) {
        int b = deg_bin(off[i + 1] - off[i]);
        int p = atomicAdd(&lh[b], 1);
        perm[lbase[b] + p] = i;
    }
}

// ============================================================================
// Fused gather-mean + linear epilogue + relu (degree-balanced via perm)
// ============================================================================

template <int FIN, int LD, int SIN, int FOUT, int SOUT>
__global__ void fused_sage(const int* __restrict__ perm,
                           const int* __restrict__ off, const int* __restrict__ ssrc,
                           const float* __restrict__ hin,
                           const float* __restrict__ wl, const float* __restrict__ bl,
                           const float* __restrict__ wr, float* __restrict__ hout) {
    __shared__ float s_wl[FOUT * FIN];
    __shared__ float s_wr[FOUT * FIN];
    __shared__ float s_b[FOUT];
    for (int t = threadIdx.x; t < FOUT * FIN; t += 256) {
        s_wl[t] = wl[t];
        s_wr[t] = wr[t];
    }
    if (threadIdx.x < FOUT) s_b[threadIdx.x] = bl[threadIdx.x];
    __syncthreads();

    int idx = blockIdx.x * 256 + threadIdx.x;
    if (idx >= N_NODES) return;
    int i = perm[idx];

    int b = off[i], e = off[i + 1];
    constexpr int NQ = LD / 4;
    constexpr int UN = (NQ >= 5) ? 3 : 4;

    float acc[LD];
#pragma unroll
    for (int k = 0; k < LD; ++k) acc[k] = 0.f;

    int k = b;
    for (; k + UN - 1 < e; k += UN) {
        int sidx[UN];
#pragma unroll
        for (int u = 0; u < UN; ++u) sidx[u] = ssrc[k + u];
        float4 v[UN][NQ];
#pragma unroll
        for (int u = 0; u < UN; ++u) {
            const float4* p = (const float4*)(hin + (long)sidx[u] * SIN);
#pragma unroll
            for (int q = 0; q < NQ; ++q) v[u][q] = p[q];
        }
#pragma unroll
        for (int u = 0; u < UN; ++u) {
#pragma unroll
            for (int q = 0; q < NQ; ++q) {
                acc[q * 4 + 0] += v[u][q].x;
                acc[q * 4 + 1] += v[u][q].y;
                acc[q * 4 + 2] += v[u][q].z;
                acc[q * 4 + 3] += v[u][q].w;
            }
        }
    }
    for (; k < e; ++k) {
        int s = ssrc[k];
        const float4* p = (const float4*)(hin + (long)s * SIN);
#pragma unroll
        for (int q = 0; q < NQ; ++q) {
            float4 vv = p[q];
            acc[q * 4 + 0] += vv.x;
            acc[q * 4 + 1] += vv.y;
            acc[q * 4 + 2] += vv.z;
            acc[q * 4 + 3] += vv.w;
        }
    }

    float inv = 1.f / fmaxf((float)(e - b), 1.f);
#pragma unroll
    for (int q = 0; q < FIN; ++q) acc[q] *= inv;

    float xv[LD];
    const float4* xp = (const float4*)(hin + (long)i * SIN);
#pragma unroll
    for (int q = 0; q < NQ; ++q) {
        float4 vv = xp[q];
        xv[q * 4 + 0] = vv.x;
        xv[q * 4 + 1] = vv.y;
        xv[q * 4 + 2] = vv.z;
        xv[q * 4 + 3] = vv.w;
    }

#pragma unroll
    for (int j = 0; j < FOUT; ++j) {
        float r = s_b[j];
#pragma unroll
        for (int kk = 0; kk < FIN; ++kk) {
            r += s_wl[j * FIN + kk] * acc[kk] + s_wr[j * FIN + kk] * xv[kk];
        }
        hout[(long)i * SOUT + j] = fmaxf(r, 0.f);
    }
}

__global__ void fused_final(const int* __restrict__ perm,
                            const int* __restrict__ off, const int* __restrict__ ssrc,
                            const float* __restrict__ hin,
                            const float* __restrict__ w3l, const float* __restrict__ b3,
                            const float* __restrict__ w3r,
                            const float* __restrict__ wc, const float* __restrict__ bc,
                            float* __restrict__ out) {
    __shared__ float s_wl[400];
    __shared__ float s_wr[400];
    __shared__ float s_b[20];
    __shared__ float s_wc[160];
    __shared__ float s_bc[8];
    for (int t = threadIdx.x; t < 400; t += 256) {
        s_wl[t] = w3l[t];
        s_wr[t] = w3r[t];
    }
    if (threadIdx.x < 160) s_wc[threadIdx.x] = wc[threadIdx.x];
    if (threadIdx.x < 20) s_b[threadIdx.x] = b3[threadIdx.x];
    if (threadIdx.x >= 32 && threadIdx.x < 40) s_bc[threadIdx.x - 32] = bc[threadIdx.x - 32];
    __syncthreads();

    int idx = blockIdx.x * 256 + threadIdx.x;
    if (idx >= N_NODES) return;
    int i = perm[idx];

    int b = off[i], e = off[i + 1];
    constexpr int NQ = 5;
    constexpr int UN = 3;

    float acc[20];
#pragma unroll
    for (int k = 0; k < 20; ++k) acc[k] = 0.f;

    int k = b;
    for (; k + UN - 1 < e; k += UN) {
        int sidx[UN];
#pragma unroll
        for (int u = 0; u < UN; ++u) sidx[u] = ssrc[k + u];
        float4 v[UN][NQ];
#pragma unroll
        for (int u = 0; u < UN; ++u) {
            const float4* p = (const float4*)(hin + (long)sidx[u] * 20);
#pragma unroll
            for (int q = 0; q < NQ; ++q) v[u][q] = p[q];
        }
#pragma unroll
        for (int u = 0; u < UN; ++u) {
#pragma unroll
            for (int q = 0; q < NQ; ++q) {
                acc[q * 4 + 0] += v[u][q].x;
                acc[q * 4 + 1] += v[u][q].y;
                acc[q * 4 + 2] += v[u][q].z;
                acc[q * 4 + 3] += v[u][q].w;
            }
        }
    }
    for (; k < e; ++k) {
        int s = ssrc[k];
        const float4* p = (const float4*)(hin + (long)s * 20);
#pragma unroll
        for (int q = 0; q < NQ; ++q) {
            float4 vv = p[q];
            acc[q * 4 + 0] += vv.x;
            acc[q * 4 + 1] += vv.y;
            acc[q * 4 + 2] += vv.z;
            acc[q * 4 + 3] += vv.w;
        }
    }

    float inv = 1.f / fmaxf((float)(e - b), 1.f);
#pragma unroll
    for (int q = 0; q < 20; ++q) acc[q] *= inv;

    float xv[20];
    const float4* xp = (const float4*)(hin + (long)i * 20);
#pragma unroll
    for (int q = 0; q < NQ; ++q) {
        float4 vv = xp[q];
        xv[q * 4 + 0] = vv.x;
        xv[q * 4 + 1] = vv.y;
        xv[q * 4 + 2] = vv.z;
        xv[q * 4 + 3] = vv.w;
    }

    float h3[20];
#pragma unroll
    for (int j = 0; j < 20; ++j) {
        float r = s_b[j];
#pragma unroll
        for (int kk = 0; kk < 20; ++kk) {
            r += s_wl[j * 20 + kk] * acc[kk] + s_wr[j * 20 + kk] * xv[kk];
        }
        h3[j] = fmaxf(r, 0.f);
    }
#pragma unroll
    for (int j = 0; j < 8; ++j) {
        float r = s_bc[j];
#pragma unroll
        for (int kk = 0; kk < 20; ++kk) {
            r += s_wc[j * 20 + kk] * h3[kk];
        }
        out[(long)i * 8 + j] = r;
    }
}

// ============================================================================
// Path B (fallback, small ws): float-atomic version
// ============================================================================

__global__ void deg_kernel(const int* __restrict__ dst, int* __restrict__ deg) {
    int i = blockIdx.x * blockDim.x + threadIdx.x;
    if (i < N_EDGES) atomicAdd(&deg[dst[i]], 1);
}

template <int F>
__global__ void edge_agg(const int* __restrict__ src, const int* __restrict__ dst,
                         const float* __restrict__ h, float* __restrict__ agg) {
    int i = blockIdx.x * blockDim.x + threadIdx.x;
    if (i >= N_EDGES) return;
    int s = src[i];
    int d = dst[i];
    const float* hs = h + (long)s * F;
    float* ad = agg + (long)d * F;
#pragma unroll
    for (int f = 0; f < F; ++f) atomicAdd(&ad[f], hs[f]);
}

template <int FIN, int FOUT>
__global__ void node_apply(const float* __restrict__ agg, const float* __restrict__ hin,
                           const int* __restrict__ deg, const float* __restrict__ wl,
                           const float* __restrict__ bl, const float* __restrict__ wr,
                           float* __restrict__ hout) {
    __shared__ float s_wl[FOUT * FIN];
    __shared__ float s_wr[FOUT * FIN];
    __shared__ float s_b[FOUT];
    for (int t = threadIdx.x; t < FOUT * FIN; t += blockDim.x) {
        s_wl[t] = wl[t];
        s_wr[t] = wr[t];
    }
    for (int t = threadIdx.x; t < FOUT; t += blockDim.x) s_b[t] = bl[t];
    __syncthreads();
    int i = blockIdx.x * blockDim.x + threadIdx.x;
    if (i >= N_NODES) return;
    float inv = 1.0f / fmaxf((float)deg[i], 1.0f);
    float a[FIN], xv[FIN];
#pragma unroll
    for (int kk = 0; kk < FIN; ++kk) {
        a[kk] = agg[(long)i * FIN + kk] * inv;
        xv[kk] = hin[(long)i * FIN + kk];
    }
#pragma unroll
    for (int j = 0; j < FOUT; ++j) {
        float r = s_b[j];
#pragma unroll
        for (int kk = 0; kk < FIN; ++kk) r += s_wl[j * FIN + kk] * a[kk] + s_wr[j * FIN + kk] * xv[kk];
        hout[(long)i * FOUT + j] = fmaxf(r, 0.f);
    }
}

__global__ void node_final_old(const float* __restrict__ agg, const float* __restrict__ hin,
                               const int* __restrict__ deg, const float* __restrict__ w3l,
                               const float* __restrict__ b3, const float* __restrict__ w3r,
                               const float* __restrict__ wc, const float* __restrict__ bc,
                               float* __restrict__ out) {
    __shared__ float s_wl[400];
    __shared__ float s_wr[400];
    __shared__ float s_b[20];
    __shared__ float s_wc[160];
    __shared__ float s_bc[8];
    for (int t = threadIdx.x; t < 400; t += blockDim.x) {
        s_wl[t] = w3l[t];
        s_wr[t] = w3r[t];
    }
    for (int t = threadIdx.x; t < 160; t += blockDim.x) s_wc[t] = wc[t];
    for (int t = threadIdx.x; t < 20; t += blockDim.x) s_b[t] = b3[t];
    for (int t = threadIdx.x; t < 8; t += blockDim.x) s_bc[t] = bc[t];
    __syncthreads();
    int i = blockIdx.x * blockDim.x + threadIdx.x;
    if (i >= N_NODES) return;
    float inv = 1.0f / fmaxf((float)deg[i], 1.0f);
    float a[20], xv[20];
#pragma unroll
    for (int kk = 0; kk < 20; ++kk) {
        a[kk] = agg[(long)i * 20 + kk] * inv;
        xv[kk] = hin[(long)i * 20 + kk];
    }
    float h3[20];
#pragma unroll
    for (int j = 0; j < 20; ++j) {
        float r = s_b[j];
#pragma unroll
        for (int kk = 0; kk < 20; ++kk) r += s_wl[j * 20 + kk] * a[kk] + s_wr[j * 20 + kk] * xv[kk];
        h3[j] = fmaxf(r, 0.f);
    }
#pragma unroll
    for (int j = 0; j < 8; ++j) {
        float r = s_bc[j];
#pragma unroll
        for (int kk = 0; kk < 20; ++kk) r += s_wc[j * 20 + kk] * h3[kk];
        out[(long)i * 8 + j] = r;
    }
}

// ============================================================================

extern "C" void kernel_launch(void* const* d_in, const int* in_sizes, int n_in,
                              void* d_out, int out_size, void* d_ws, size_t ws_size,
                              hipStream_t stream) {
    const float* x = (const float*)d_in[0];
    const int* ei = (const int*)d_in[1];  // [2, E]: src row then dst row
    const float* w1l = (const float*)d_in[2];
    const float* b1 = (const float*)d_in[3];
    const float* w1r = (const float*)d_in[4];
    const float* w2l = (const float*)d_in[5];
    const float* b2 = (const float*)d_in[6];
    const float* w2r = (const float*)d_in[7];
    const float* w3l = (const float*)d_in[8];
    const float* b3 = (const float*)d_in[9];
    const float* w3r = (const float*)d_in[10];
    const float* wc = (const float*)d_in[11];
    const float* bc = (const float*)d_in[12];
    float* out = (float*)d_out;

    const int* src = ei;
    const int* dst = ei + N_EDGES;

    const int BT = 256;
    dim3 blk(BT);
    dim3 egrid((N_EDGES + BT - 1) / BT);
    dim3 ngrid(NB);

    // ---- Path A v3 layout (bytes):
    // off    [0,          2,000,128)   500001 ints (padded)
    // bbase  [2,000,128,  2,004,352)   1025 ints (padded)
    // gcur   [2,004,352,  2,008,448)   1024 ints
    // dcur   [2,008,448,  2,009,472)   256 ints
    // perm   [2,009,472,  4,009,472)   500K ints
    // P      [4,009,600,  68,009,600)  16M packed ints; h1/h2 overlay after fine_sort
    // S      [68,009,600, 132,009,600) 16M sorted src
    const size_t NEED_A = 132009600;

    if (ws_size >= NEED_A) {
        char* ws = (char*)d_ws;
        int* off = (int*)ws;
        int* bbase = (int*)(ws + 2000128);
        int* gcur = (int*)(ws + 2004352);
        int* dcur = (int*)(ws + 2008448);
        int* perm = (int*)(ws + 2009472);
        int* P = (int*)(ws + 4009600);
        int* S = (int*)(ws + 68009600);
        float* h1 = (float*)(ws + 4009600);              // overlays P (dead after fine_sort)
        float* h2 = (float*)(ws + 4009600 + 24000000);

        hipMemsetAsync(gcur, 0, (NBUCK_PAD + DBINS) * sizeof(int), stream);  // gcur + dcur
        bucket_hist<<<1024, blk, 0, stream>>>(dst, gcur);
        bucket_scan<<<1, blk, 0, stream>>>(gcur, bbase);
        bucket_scatter<<<NSB, blk, 0, stream>>>(src, dst, gcur, P);
        fine_sort<<<NBUCK, blk, 0, stream>>>(P, bbase, off, S);

        // degree-balanced node order (heaviest first)
        deg_hist<<<NDB, blk, 0, stream>>>(off, dcur);
        deg_scan<<<1, blk, 0, stream>>>(dcur);
        deg_scatter<<<NDB, blk, 0, stream>>>(off, dcur, perm);

        fused_sage<4, 4, 4, 10, 12><<<ngrid, blk, 0, stream>>>(perm, off, S, x, w1l, b1, w1r, h1);
        fused_sage<10, 12, 12, 20, 20><<<ngrid, blk, 0, stream>>>(perm, off, S, h1, w2l, b2, w2r, h2);
        fused_final<<<ngrid, blk, 0, stream>>>(perm, off, S, h2, w3l, b3, w3r, wc, bc, out);
    } else {
        // fallback: float-atomic path (needs 102 MB)
        char* ws = (char*)d_ws;
        int* deg = (int*)ws;
        float* agg = (float*)(ws + 2000000);
        float* h1 = (float*)(ws + 42000000);
        float* h2 = (float*)(ws + 62000000);

        hipMemsetAsync(deg, 0, (size_t)N_NODES * sizeof(int), stream);
        deg_kernel<<<egrid, blk, 0, stream>>>(dst, deg);

        hipMemsetAsync(agg, 0, (size_t)N_NODES * 4 * sizeof(float), stream);
        edge_agg<4><<<egrid, blk, 0, stream>>>(src, dst, x, agg);
        node_apply<4, 10><<<ngrid, blk, 0, stream>>>(agg, x, deg, w1l, b1, w1r, h1);

        hipMemsetAsync(agg, 0, (size_t)N_NODES * 10 * sizeof(float), stream);
        edge_agg<10><<<egrid, blk, 0, stream>>>(src, dst, h1, agg);
        node_apply<10, 20><<<ngrid, blk, 0, stream>>>(agg, h1, deg, w2l, b2, w2r, h2);

        hipMemsetAsync(agg, 0, (size_t)N_NODES * 20 * sizeof(float), stream);
        edge_agg<20><<<egrid, blk, 0, stream>>>(src, dst, h2, agg);
        node_final_old<<<ngrid, blk, 0, stream>>>(agg, h2, deg, w3l, b3, w3r, wc, bc, out);
    }
}

// Round 5
// 1660.842 us; speedup vs baseline: 1.1997x; 1.1997x over previous
//
#include <hip/hip_runtime.h>
#include <hip/hip_fp16.h>

#define N_NODES 500000
#define N_EDGES 16000000
#define NB 1954          // ceil(N_NODES/256)
#define NPB_LOG 9
#define NPB 512          // nodes per bucket
#define NBUCK 977        // ceil(N_NODES/NPB)
#define NBUCK_PAD 1024
#define CH 32768         // edges per bucket_scatter block
#define NSB 489          // ceil(N_EDGES/CH)

// ---------- fp16 pack/unpack helpers (fp32 math everywhere else) ----------
__device__ __forceinline__ float2 up2(int p) {
    __half2 h = *reinterpret_cast<__half2*>(&p);
    return __half22float2(h);
}
__device__ __forceinline__ int pk2(float a, float b) {
    __half2 h = __floats2half2_rn(a, b);
    return *reinterpret_cast<int*>(&h);
}

// ============================================================================
// Two-level counting sort (LDS atomics) -> CSR (off, S)
// ============================================================================

__global__ void bucket_hist(const int* __restrict__ dst, int* __restrict__ ghist) {
    __shared__ int lhist[NBUCK_PAD];
    for (int t = threadIdx.x; t < NBUCK_PAD; t += 256) lhist[t] = 0;
    __syncthreads();
    int stride = gridDim.x * 256;
    for (int i = blockIdx.x * 256 + threadIdx.x; i < N_EDGES; i += stride) {
        atomicAdd(&lhist[dst[i] >> NPB_LOG], 1);
    }
    __syncthreads();
    for (int t = threadIdx.x; t < NBUCK_PAD; t += 256) {
        int c = lhist[t];
        if (c) atomicAdd(&ghist[t], c);
    }
}

__global__ void bucket_scan(int* __restrict__ gcur, int* __restrict__ bbase) {
    __shared__ int s[256];
    int t = threadIdx.x;
    int v[4], sum = 0, loc[4];
#pragma unroll
    for (int j = 0; j < 4; ++j) {
        v[j] = gcur[t * 4 + j];
        loc[j] = sum;
        sum += v[j];
    }
    s[t] = sum;
    __syncthreads();
    for (int o = 1; o < 256; o <<= 1) {
        int x = (t >= o) ? s[t - o] : 0;
        __syncthreads();
        s[t] += x;
        __syncthreads();
    }
    int excl = s[t] - sum;
#pragma unroll
    for (int j = 0; j < 4; ++j) {
        int e = excl + loc[j];
        bbase[t * 4 + j] = e;
        gcur[t * 4 + j] = e;
    }
    if (t == 255) bbase[NBUCK_PAD] = s[255];
}

__global__ void bucket_scatter(const int* __restrict__ src, const int* __restrict__ dst,
                               int* __restrict__ gcur, int* __restrict__ P) {
    __shared__ int lhist[NBUCK_PAD];
    __shared__ int lcur[NBUCK_PAD];
    for (int t = threadIdx.x; t < NBUCK_PAD; t += 256) lhist[t] = 0;
    __syncthreads();
    int e0 = blockIdx.x * CH;
    int e1 = min(e0 + CH, N_EDGES);
    for (int i = e0 + threadIdx.x; i < e1; i += 256) {
        atomicAdd(&lhist[dst[i] >> NPB_LOG], 1);
    }
    __syncthreads();
    for (int t = threadIdx.x; t < NBUCK_PAD; t += 256) {
        int c = lhist[t];
        lcur[t] = c ? atomicAdd(&gcur[t], c) : 0;
    }
    __syncthreads();
    for (int i = e0 + threadIdx.x; i < e1; i += 256) {
        int d = dst[i];
        int s = src[i];
        int b = d >> NPB_LOG;
        int pos = atomicAdd(&lcur[b], 1);
        P[pos] = ((d & (NPB - 1)) << 19) | s;
    }
}

__global__ void fine_sort(const int* __restrict__ P, const int* __restrict__ bbase,
                          int* __restrict__ off, int* __restrict__ S) {
    __shared__ int lhist[NPB];
    __shared__ int lexcl[NPB];
    __shared__ int sscan[256];
    int t = threadIdx.x;
    int b = blockIdx.x;
    int bb = bbase[b];
    int be = bbase[b + 1];
    int node0 = b << NPB_LOG;

    lhist[t] = 0;
    lhist[t + 256] = 0;
    __syncthreads();
    for (int j = bb + t; j < be; j += 256) {
        atomicAdd(&lhist[P[j] >> 19], 1);
    }
    __syncthreads();

    int a0 = lhist[2 * t], a1 = lhist[2 * t + 1];
    int ps = a0 + a1;
    sscan[t] = ps;
    __syncthreads();
    for (int o = 1; o < 256; o <<= 1) {
        int x = (t >= o) ? sscan[t - o] : 0;
        __syncthreads();
        sscan[t] += x;
        __syncthreads();
    }
    int pe = sscan[t] - ps;
    lexcl[2 * t] = pe;
    lexcl[2 * t + 1] = pe + a0;
    __syncthreads();

#pragma unroll
    for (int j = 0; j < 2; ++j) {
        int idx = t + j * 256;
        int ng = node0 + idx;
        if (ng < N_NODES) off[ng] = bb + lexcl[idx];
        lhist[idx] = lexcl[idx];
    }
    if (b == NBUCK - 1 && t == 0) off[N_NODES] = N_EDGES;
    __syncthreads();

    for (int j = bb + t; j < be; j += 256) {
        int p = P[j];
        int n = p >> 19;
        int s = p & 0x7FFFF;
        int pos = atomicAdd(&lhist[n], 1);
        S[bb + pos] = s;
    }
}

// ============================================================================
// fp16 table prep: x (fp32, 4 feats) -> xh (fp16, 8 B rows)
// ============================================================================

__global__ void convert_x(const float* __restrict__ x, int2* __restrict__ xh) {
    int i = blockIdx.x * 256 + threadIdx.x;
    if (i >= N_NODES) return;
    float4 v = ((const float4*)x)[i];
    int2 r;
    r.x = pk2(v.x, v.y);
    r.y = pk2(v.z, v.w);
    xh[i] = r;
}

// ============================================================================
// Fused layers, fp16 gather tables, fp32 math
// ============================================================================

// Layer 1: gather xh (8 B rows), self from fp32 x, out h1 fp16 (20 B in 32 B stride)
__global__ __launch_bounds__(256, 4) void fused_l1(
        const int* __restrict__ off, const int* __restrict__ ssrc,
        const int2* __restrict__ xh, const float* __restrict__ x,
        const float* __restrict__ wl, const float* __restrict__ bl,
        const float* __restrict__ wr, int* __restrict__ h1) {
    __shared__ float s_wl[40];
    __shared__ float s_wr[40];
    __shared__ float s_b[10];
    if (threadIdx.x < 40) {
        s_wl[threadIdx.x] = wl[threadIdx.x];
        s_wr[threadIdx.x] = wr[threadIdx.x];
    }
    if (threadIdx.x >= 64 && threadIdx.x < 74) s_b[threadIdx.x - 64] = bl[threadIdx.x - 64];
    __syncthreads();

    int i = blockIdx.x * 256 + threadIdx.x;
    if (i >= N_NODES) return;

    int b = off[i], e = off[i + 1];
    constexpr int UN = 8;

    float acc[4] = {0.f, 0.f, 0.f, 0.f};

    int k = b;
    for (; k + UN - 1 < e; k += UN) {
        int sidx[UN];
#pragma unroll
        for (int u = 0; u < UN; ++u) sidx[u] = ssrc[k + u];
        int2 v[UN];
#pragma unroll
        for (int u = 0; u < UN; ++u) v[u] = xh[sidx[u]];
#pragma unroll
        for (int u = 0; u < UN; ++u) {
            float2 f0 = up2(v[u].x), f1 = up2(v[u].y);
            acc[0] += f0.x; acc[1] += f0.y; acc[2] += f1.x; acc[3] += f1.y;
        }
    }
    for (; k < e; ++k) {
        int2 v = xh[ssrc[k]];
        float2 f0 = up2(v.x), f1 = up2(v.y);
        acc[0] += f0.x; acc[1] += f0.y; acc[2] += f1.x; acc[3] += f1.y;
    }

    float inv = 1.f / fmaxf((float)(e - b), 1.f);
#pragma unroll
    for (int q = 0; q < 4; ++q) acc[q] *= inv;

    float4 xs = ((const float4*)x)[i];
    float xv[4] = {xs.x, xs.y, xs.z, xs.w};

    float r[10];
#pragma unroll
    for (int j = 0; j < 10; ++j) {
        float t = s_b[j];
#pragma unroll
        for (int kk = 0; kk < 4; ++kk) {
            t += s_wl[j * 4 + kk] * acc[kk] + s_wr[j * 4 + kk] * xv[kk];
        }
        r[j] = fmaxf(t, 0.f);
    }
    // pack 10 halves -> int4 + int at 32 B stride (8 ints)
    int4 o0;
    o0.x = pk2(r[0], r[1]); o0.y = pk2(r[2], r[3]);
    o0.z = pk2(r[4], r[5]); o0.w = pk2(r[6], r[7]);
    *(int4*)(h1 + (long)i * 8) = o0;
    h1[(long)i * 8 + 4] = pk2(r[8], r[9]);
}

// Layer 2: gather h1 (20 B rows in 32 B stride), out h2 fp16 (40 B in 64 B stride)
__global__ __launch_bounds__(256, 4) void fused_l2(
        const int* __restrict__ off, const int* __restrict__ ssrc,
        const int* __restrict__ h1,
        const float* __restrict__ wl, const float* __restrict__ bl,
        const float* __restrict__ wr, int* __restrict__ h2) {
    __shared__ float s_wl[200];
    __shared__ float s_wr[200];
    __shared__ float s_b[20];
    if (threadIdx.x < 200) {
        s_wl[threadIdx.x] = wl[threadIdx.x];
        s_wr[threadIdx.x] = wr[threadIdx.x];
    }
    if (threadIdx.x >= 224 && threadIdx.x < 244) s_b[threadIdx.x - 224] = bl[threadIdx.x - 224];
    __syncthreads();

    int i = blockIdx.x * 256 + threadIdx.x;
    if (i >= N_NODES) return;

    int b = off[i], e = off[i + 1];
    constexpr int UN = 4;

    float acc[10];
#pragma unroll
    for (int q = 0; q < 10; ++q) acc[q] = 0.f;

    int k = b;
    for (; k + UN - 1 < e; k += UN) {
        int sidx[UN];
#pragma unroll
        for (int u = 0; u < UN; ++u) sidx[u] = ssrc[k + u];
        int4 v4[UN];
        int v1[UN];
#pragma unroll
        for (int u = 0; u < UN; ++u) {
            const int* row = h1 + (long)sidx[u] * 8;
            v4[u] = *(const int4*)row;
            v1[u] = row[4];
        }
#pragma unroll
        for (int u = 0; u < UN; ++u) {
            float2 f0 = up2(v4[u].x), f1 = up2(v4[u].y), f2 = up2(v4[u].z), f3 = up2(v4[u].w), f4 = up2(v1[u]);
            acc[0] += f0.x; acc[1] += f0.y; acc[2] += f1.x; acc[3] += f1.y;
            acc[4] += f2.x; acc[5] += f2.y; acc[6] += f3.x; acc[7] += f3.y;
            acc[8] += f4.x; acc[9] += f4.y;
        }
    }
    for (; k < e; ++k) {
        const int* row = h1 + (long)ssrc[k] * 8;
        int4 v4 = *(const int4*)row;
        int v1 = row[4];
        float2 f0 = up2(v4.x), f1 = up2(v4.y), f2 = up2(v4.z), f3 = up2(v4.w), f4 = up2(v1);
        acc[0] += f0.x; acc[1] += f0.y; acc[2] += f1.x; acc[3] += f1.y;
        acc[4] += f2.x; acc[5] += f2.y; acc[6] += f3.x; acc[7] += f3.y;
        acc[8] += f4.x; acc[9] += f4.y;
    }

    float inv = 1.f / fmaxf((float)(e - b), 1.f);
#pragma unroll
    for (int q = 0; q < 10; ++q) acc[q] *= inv;

    float xv[10];
    {
        const int* row = h1 + (long)i * 8;
        int4 v4 = *(const int4*)row;
        int v1 = row[4];
        float2 f0 = up2(v4.x), f1 = up2(v4.y), f2 = up2(v4.z), f3 = up2(v4.w), f4 = up2(v1);
        xv[0] = f0.x; xv[1] = f0.y; xv[2] = f1.x; xv[3] = f1.y;
        xv[4] = f2.x; xv[5] = f2.y; xv[6] = f3.x; xv[7] = f3.y;
        xv[8] = f4.x; xv[9] = f4.y;
    }

    float r[20];
#pragma unroll
    for (int j = 0; j < 20; ++j) {
        float t = s_b[j];
#pragma unroll
        for (int kk = 0; kk < 10; ++kk) {
            t += s_wl[j * 10 + kk] * acc[kk] + s_wr[j * 10 + kk] * xv[kk];
        }
        r[j] = fmaxf(t, 0.f);
    }
    // pack 20 halves -> int4 + int4 + int2 at 64 B stride (16 ints)
    int* o = h2 + (long)i * 16;
    int4 o0, o1;
    o0.x = pk2(r[0], r[1]);   o0.y = pk2(r[2], r[3]);
    o0.z = pk2(r[4], r[5]);   o0.w = pk2(r[6], r[7]);
    o1.x = pk2(r[8], r[9]);   o1.y = pk2(r[10], r[11]);
    o1.z = pk2(r[12], r[13]); o1.w = pk2(r[14], r[15]);
    *(int4*)o = o0;
    *(int4*)(o + 4) = o1;
    int2 o2;
    o2.x = pk2(r[16], r[17]); o2.y = pk2(r[18], r[19]);
    *(int2*)(o + 8) = o2;
}

// Layer 3 + classifier: gather h2 (40 B rows in 64 B stride), out fp32
__global__ __launch_bounds__(256, 4) void fused_l3(
        const int* __restrict__ off, const int* __restrict__ ssrc,
        const int* __restrict__ h2,
        const float* __restrict__ w3l, const float* __restrict__ b3,
        const float* __restrict__ w3r,
        const float* __restrict__ wc, const float* __restrict__ bc,
        float* __restrict__ out) {
    __shared__ float s_wl[400];
    __shared__ float s_wr[400];
    __shared__ float s_b[20];
    __shared__ float s_wc[160];
    __shared__ float s_bc[8];
    for (int t = threadIdx.x; t < 400; t += 256) {
        s_wl[t] = w3l[t];
        s_wr[t] = w3r[t];
    }
    if (threadIdx.x < 160) s_wc[threadIdx.x] = wc[threadIdx.x];
    if (threadIdx.x >= 192 && threadIdx.x < 212) s_b[threadIdx.x - 192] = b3[threadIdx.x - 192];
    if (threadIdx.x >= 224 && threadIdx.x < 232) s_bc[threadIdx.x - 224] = bc[threadIdx.x - 224];
    __syncthreads();

    int i = blockIdx.x * 256 + threadIdx.x;
    if (i >= N_NODES) return;

    int b = off[i], e = off[i + 1];
    constexpr int UN = 4;

    float acc[20];
#pragma unroll
    for (int q = 0; q < 20; ++q) acc[q] = 0.f;

    int k = b;
    for (; k + UN - 1 < e; k += UN) {
        int sidx[UN];
#pragma unroll
        for (int u = 0; u < UN; ++u) sidx[u] = ssrc[k + u];
        int4 va[UN], vb[UN];
        int2 vc[UN];
#pragma unroll
        for (int u = 0; u < UN; ++u) {
            const int* row = h2 + (long)sidx[u] * 16;
            va[u] = *(const int4*)row;
            vb[u] = *(const int4*)(row + 4);
            vc[u] = *(const int2*)(row + 8);
        }
#pragma unroll
        for (int u = 0; u < UN; ++u) {
            float2 f;
            f = up2(va[u].x); acc[0] += f.x; acc[1] += f.y;
            f = up2(va[u].y); acc[2] += f.x; acc[3] += f.y;
            f = up2(va[u].z); acc[4] += f.x; acc[5] += f.y;
            f = up2(va[u].w); acc[6] += f.x; acc[7] += f.y;
            f = up2(vb[u].x); acc[8] += f.x; acc[9] += f.y;
            f = up2(vb[u].y); acc[10] += f.x; acc[11] += f.y;
            f = up2(vb[u].z); acc[12] += f.x; acc[13] += f.y;
            f = up2(vb[u].w); acc[14] += f.x; acc[15] += f.y;
            f = up2(vc[u].x); acc[16] += f.x; acc[17] += f.y;
            f = up2(vc[u].y); acc[18] += f.x; acc[19] += f.y;
        }
    }
    for (; k < e; ++k) {
        const int* row = h2 + (long)ssrc[k] * 16;
        int4 va = *(const int4*)row;
        int4 vb = *(const int4*)(row + 4);
        int2 vc = *(const int2*)(row + 8);
        float2 f;
        f = up2(va.x); acc[0] += f.x; acc[1] += f.y;
        f = up2(va.y); acc[2] += f.x; acc[3] += f.y;
        f = up2(va.z); acc[4] += f.x; acc[5] += f.y;
        f = up2(va.w); acc[6] += f.x; acc[7] += f.y;
        f = up2(vb.x); acc[8] += f.x; acc[9] += f.y;
        f = up2(vb.y); acc[10] += f.x; acc[11] += f.y;
        f = up2(vb.z); acc[12] += f.x; acc[13] += f.y;
        f = up2(vb.w); acc[14] += f.x; acc[15] += f.y;
        f = up2(vc.x); acc[16] += f.x; acc[17] += f.y;
        f = up2(vc.y); acc[18] += f.x; acc[19] += f.y;
    }

    float inv = 1.f / fmaxf((float)(e - b), 1.f);
#pragma unroll
    for (int q = 0; q < 20; ++q) acc[q] *= inv;

    float xv[20];
    {
        const int* row = h2 + (long)i * 16;
        int4 va = *(const int4*)row;
        int4 vb = *(const int4*)(row + 4);
        int2 vc = *(const int2*)(row + 8);
        float2 f;
        f = up2(va.x); xv[0] = f.x; xv[1] = f.y;
        f = up2(va.y); xv[2] = f.x; xv[3] = f.y;
        f = up2(va.z); xv[4] = f.x; xv[5] = f.y;
        f = up2(va.w); xv[6] = f.x; xv[7] = f.y;
        f = up2(vb.x); xv[8] = f.x; xv[9] = f.y;
        f = up2(vb.y); xv[10] = f.x; xv[11] = f.y;
        f = up2(vb.z); xv[12] = f.x; xv[13] = f.y;
        f = up2(vb.w); xv[14] = f.x; xv[15] = f.y;
        f = up2(vc.x); xv[16] = f.x; xv[17] = f.y;
        f = up2(vc.y); xv[18] = f.x; xv[19] = f.y;
    }

    float h3[20];
#pragma unroll
    for (int j = 0; j < 20; ++j) {
        float r = s_b[j];
#pragma unroll
        for (int kk = 0; kk < 20; ++kk) {
            r += s_wl[j * 20 + kk] * acc[kk] + s_wr[j * 20 + kk] * xv[kk];
        }
        h3[j] = fmaxf(r, 0.f);
    }
#pragma unroll
    for (int j = 0; j < 8; ++j) {
        float r = s_bc[j];
#pragma unroll
        for (int kk = 0; kk < 20; ++kk) {
            r += s_wc[j * 20 + kk] * h3[kk];
        }
        out[(long)i * 8 + j] = r;
    }
}

// ============================================================================
// Path B (fallback, small ws): float-atomic version
// ============================================================================

__global__ void deg_kernel(const int* __restrict__ dst, int* __restrict__ deg) {
    int i = blockIdx.x * blockDim.x + threadIdx.x;
    if (i < N_EDGES) atomicAdd(&deg[dst[i]], 1);
}

template <int F>
__global__ void edge_agg(const int* __restrict__ src, const int* __restrict__ dst,
                         const float* __restrict__ h, float* __restrict__ agg) {
    int i = blockIdx.x * blockDim.x + threadIdx.x;
    if (i >= N_EDGES) return;
    int s = src[i];
    int d = dst[i];
    const float* hs = h + (long)s * F;
    float* ad = agg + (long)d * F;
#pragma unroll
    for (int f = 0; f < F; ++f) atomicAdd(&ad[f], hs[f]);
}

template <int FIN, int FOUT>
__global__ void node_apply(const float* __restrict__ agg, const float* __restrict__ hin,
                           const int* __restrict__ deg, const float* __restrict__ wl,
                           const float* __restrict__ bl, const float* __restrict__ wr,
                           float* __restrict__ hout) {
    __shared__ float s_wl[FOUT * FIN];
    __shared__ float s_wr[FOUT * FIN];
    __shared__ float s_b[FOUT];
    for (int t = threadIdx.x; t < FOUT * FIN; t += blockDim.x) {
        s_wl[t] = wl[t];
        s_wr[t] = wr[t];
    }
    for (int t = threadIdx.x; t < FOUT; t += blockDim.x) s_b[t] = bl[t];
    __syncthreads();
    int i = blockIdx.x * blockDim.x + threadIdx.x;
    if (i >= N_NODES) return;
    float inv = 1.0f / fmaxf((float)deg[i], 1.0f);
    float a[FIN], xv[FIN];
#pragma unroll
    for (int kk = 0; kk < FIN; ++kk) {
        a[kk] = agg[(long)i * FIN + kk] * inv;
        xv[kk] = hin[(long)i * FIN + kk];
    }
#pragma unroll
    for (int j = 0; j < FOUT; ++j) {
        float r = s_b[j];
#pragma unroll
        for (int kk = 0; kk < FIN; ++kk) r += s_wl[j * FIN + kk] * a[kk] + s_wr[j * FIN + kk] * xv[kk];
        hout[(long)i * FOUT + j] = fmaxf(r, 0.f);
    }
}

__global__ void node_final_old(const float* __restrict__ agg, const float* __restrict__ hin,
                               const int* __restrict__ deg, const float* __restrict__ w3l,
                               const float* __restrict__ b3, const float* __restrict__ w3r,
                               const float* __restrict__ wc, const float* __restrict__ bc,
                               float* __restrict__ out) {
    __shared__ float s_wl[400];
    __shared__ float s_wr[400];
    __shared__ float s_b[20];
    __shared__ float s_wc[160];
    __shared__ float s_bc[8];
    for (int t = threadIdx.x; t < 400; t += blockDim.x) {
        s_wl[t] = w3l[t];
        s_wr[t] = w3r[t];
    }
    for (int t = threadIdx.x; t < 160; t += blockDim.x) s_wc[t] = wc[t];
    for (int t = threadIdx.x; t < 20; t += blockDim.x) s_b[t] = b3[t];
    for (int t = threadIdx.x; t < 8; t += blockDim.x) s_bc[t] = bc[t];
    __syncthreads();
    int i = blockIdx.x * blockDim.x + threadIdx.x;
    if (i >= N_NODES) return;
    float inv = 1.0f / fmaxf((float)deg[i], 1.0f);
    float a[20], xv[20];
#pragma unroll
    for (int kk = 0; kk < 20; ++kk) {
        a[kk] = agg[(long)i * 20 + kk] * inv;
        xv[kk] = hin[(long)i * 20 + kk];
    }
    float h3[20];
#pragma unroll
    for (int j = 0; j < 20; ++j) {
        float r = s_b[j];
#pragma unroll
        for (int kk = 0; kk < 20; ++kk) r += s_wl[j * 20 + kk] * a[kk] + s_wr[j * 20 + kk] * xv[kk];
        h3[j] = fmaxf(r, 0.f);
    }
#pragma unroll
    for (int j = 0; j < 8; ++j) {
        float r = s_bc[j];
#pragma unroll
        for (int kk = 0; kk < 20; ++kk) r += s_wc[j * 20 + kk] * h3[kk];
        out[(long)i * 8 + j] = r;
    }
}

// ============================================================================

extern "C" void kernel_launch(void* const* d_in, const int* in_sizes, int n_in,
                              void* d_out, int out_size, void* d_ws, size_t ws_size,
                              hipStream_t stream) {
    const float* x = (const float*)d_in[0];
    const int* ei = (const int*)d_in[1];  // [2, E]: src row then dst row
    const float* w1l = (const float*)d_in[2];
    const float* b1 = (const float*)d_in[3];
    const float* w1r = (const float*)d_in[4];
    const float* w2l = (const float*)d_in[5];
    const float* b2 = (const float*)d_in[6];
    const float* w2r = (const float*)d_in[7];
    const float* w3l = (const float*)d_in[8];
    const float* b3 = (const float*)d_in[9];
    const float* w3r = (const float*)d_in[10];
    const float* wc = (const float*)d_in[11];
    const float* bc = (const float*)d_in[12];
    float* out = (float*)d_out;

    const int* src = ei;
    const int* dst = ei + N_EDGES;

    const int BT = 256;
    dim3 blk(BT);
    dim3 egrid((N_EDGES + BT - 1) / BT);
    dim3 ngrid(NB);

    // ---- Path A v4 layout (bytes):
    // off    [0,          2,000,128)   500001 ints (padded)
    // bbase  [2,000,128,  2,004,352)   1025 ints (padded)
    // gcur   [2,004,352,  2,008,448)   1024 ints
    // P      [2,008,448,  66,008,448)  16M packed ints (dead after fine_sort)
    //   xh   [2,008,448,  6,008,448)   overlay: 500K x 8 B fp16 rows
    //   h1   [6,008,448, 22,008,448)   overlay: 500K x 32 B fp16 rows
    //   h2   [22,008,448, 54,008,448)  overlay: 500K x 64 B fp16 rows
    // S      [66,008,448, 130,008,448) 16M sorted src
    const size_t NEED_A = 130008448;

    if (ws_size >= NEED_A) {
        char* ws = (char*)d_ws;
        int* off = (int*)ws;
        int* bbase = (int*)(ws + 2000128);
        int* gcur = (int*)(ws + 2004352);
        int* P = (int*)(ws + 2008448);
        int2* xh = (int2*)(ws + 2008448);
        int* h1 = (int*)(ws + 6008448);
        int* h2 = (int*)(ws + 22008448);
        int* S = (int*)(ws + 66008448);

        hipMemsetAsync(gcur, 0, NBUCK_PAD * sizeof(int), stream);
        bucket_hist<<<1024, blk, 0, stream>>>(dst, gcur);
        bucket_scan<<<1, blk, 0, stream>>>(gcur, bbase);
        bucket_scatter<<<NSB, blk, 0, stream>>>(src, dst, gcur, P);
        fine_sort<<<NBUCK, blk, 0, stream>>>(P, bbase, off, S);

        convert_x<<<ngrid, blk, 0, stream>>>(x, xh);
        fused_l1<<<ngrid, blk, 0, stream>>>(off, S, xh, x, w1l, b1, w1r, h1);
        fused_l2<<<ngrid, blk, 0, stream>>>(off, S, h1, w2l, b2, w2r, h2);
        fused_l3<<<ngrid, blk, 0, stream>>>(off, S, h2, w3l, b3, w3r, wc, bc, out);
    } else {
        // fallback: float-atomic path (needs 102 MB)
        char* ws = (char*)d_ws;
        int* deg = (int*)ws;
        float* agg = (float*)(ws + 2000000);
        float* h1 = (float*)(ws + 42000000);
        float* h2 = (float*)(ws + 62000000);

        hipMemsetAsync(deg, 0, (size_t)N_NODES * sizeof(int), stream);
        deg_kernel<<<egrid, blk, 0, stream>>>(dst, deg);

        hipMemsetAsync(agg, 0, (size_t)N_NODES * 4 * sizeof(float), stream);
        edge_agg<4><<<egrid, blk, 0, stream>>>(src, dst, x, agg);
        node_apply<4, 10><<<ngrid, blk, 0, stream>>>(agg, x, deg, w1l, b1, w1r, h1);

        hipMemsetAsync(agg, 0, (size_t)N_NODES * 10 * sizeof(float), stream);
        edge_agg<10><<<egrid, blk, 0, stream>>>(src, dst, h1, agg);
        node_apply<10, 20><<<ngrid, blk, 0, stream>>>(agg, h1, deg, w2l, b2, w2r, h2);

        hipMemsetAsync(agg, 0, (size_t)N_NODES * 20 * sizeof(float), stream);
        edge_agg<20><<<egrid, blk, 0, stream>>>(src, dst, h2, agg);
        node_final_old<<<ngrid, blk, 0, stream>>>(agg, h2, deg, w3l, b3, w3r, wc, bc, out);
    }
}